// Round 13
// baseline (4741.317 us; speedup 1.0000x reference)
//
#include <hip/hip_runtime.h>
#include <hip/hip_bf16.h>
#include <cstdint>
#include <cstddef>

// Problem dims
#define BB    128
#define SS    1024
#define INDIM 16
#define HH    256
#define EE    32
#define NEMB_ 64

// Decomposition
#define NGRP 8    // batch groups
#define MB   16   // batches per group
#define NCHK 8    // hidden chunks (8 blocks per group)
#define HC   32   // hidden units per chunk (block computes 4*HC=128 gate cols)
#define NTHR 256  // 4 waves; wave w owns gate-type w
#define NBLK 64   // 8 groups x 8 chunks

// Fast-poll discipline: a legit same-XCD detect takes <10 iterations.
// If a step needs more than FAST_SOFT iters, the thread permanently falls
// back to the slow (memory-side) buffer -> no hang, bounded worst case.
#define FAST_SOFT 512

using frag_t = __attribute__((ext_vector_type(8))) short;  // 8 bf16 (4 VGPRs)
using f32x4  = __attribute__((ext_vector_type(4))) float;
using i32x4  = __attribute__((ext_vector_type(4))) int;
typedef unsigned long long ull;

#define AL(p)    __hip_atomic_load((p),  __ATOMIC_RELAXED, __HIP_MEMORY_SCOPE_AGENT)

// LDS-only barrier: does NOT drain vmcnt (unlike __syncthreads), so global
// loads/stores stay in flight across it. lgkmcnt(0) orders the ds_writes.
#define LBAR() do { asm volatile("s_waitcnt lgkmcnt(0)" ::: "memory"); \
  __builtin_amdgcn_s_barrier(); __builtin_amdgcn_sched_barrier(0); } while (0)

__device__ __forceinline__ short f2bf(float f) {
  union { float f; uint32_t u; } v; v.f = f;
  uint32_t r = (v.u + 0x7fffu + ((v.u >> 16) & 1u)) >> 16;  // RNE
  return (short)(uint16_t)r;
}
__device__ __forceinline__ float sigf(float x) { return 1.0f / (1.0f + __expf(-x)); }
__device__ __forceinline__ float tanh_fast(float x) { return 1.0f - 2.0f / (__expf(2.0f * x) + 1.0f); }

// Exchange: hx*[par][g][row=batch][slot=hidden_pair] : u64 = (tag<<32)|(2xbf16).
// hxS: slow buffer, published via memory-side atomic swap sc1 (R9/R12 proven).
// hxF: fast buffer, published via PLAIN store (write-through to the producer's
//      XCD L2), polled via sc0 loads (L0-bypass, served by the same L2 when
//      consumer is on the same XCD). NO atomics touch hxF (the R4/R5 deadlock
//      was atomic-signal[memory-side] vs sc0-poll[L2-cached] divergence).

__global__ __launch_bounds__(NTHR, 1)
void ilstm_kernel(const int* __restrict__ e, const float* __restrict__ x,
                  const float* __restrict__ embt, const float* __restrict__ Wx1,
                  const float* __restrict__ Wx2, const float* __restrict__ Wh1,
                  const float* __restrict__ Wh2, const float* __restrict__ b1,
                  const float* __restrict__ b2, const float* __restrict__ We,
                  const float* __restrict__ be, const float* __restrict__ linW,
                  const float* __restrict__ linb, float* __restrict__ out,
                  ull* __restrict__ hxS, ull* __restrict__ hxF,
                  float* __restrict__ partial, int use_partial)
{
  const int tid  = threadIdx.x;
  const int bid  = blockIdx.x;
  const int g    = bid & 7;        // batch group (fast path bets this == XCD id)
  const int ch   = bid >> 3;       // hidden chunk
  const int j0   = ch * HC;
  const int lane = tid & 63;
  const int wv   = tid >> 6;       // wave id == gate type (i,f,g,o)
  const int lo4  = lane & 15;
  const int hi2  = lane >> 4;

  __shared__ unsigned short ldsW[HH * 128];      // 64KB weight staging (bf16 bits)
  __shared__ unsigned hstageU[MB][132];          // 8.4KB h tile (u32 = 2 bf16), padded
  __shared__ float alphaTab[NEMB_][HC];          // 8KB  sigmoid(emb@We+be) per emb idx
  __shared__ float gatesLds[4][MB][HC + 1];      // gate exchange, padded
  __shared__ float redbuf[MB][MB];               // [jpair][batch] out partials
  __shared__ float biasLds[2][128];
  __shared__ float linWs[HC];

  // ---------------- init: weights -> B-fragments in VGPRs ----------------
  frag_t fB[2][2][9];  // [W1/W2][ntile][kstep]; kstep 8 = x-projection (K rows 16..31 zero)
  #pragma unroll
  for (int ws = 0; ws < 2; ++ws) {
    const float* W = ws ? Wh2 : Wh1;
    for (int idx = tid; idx < HH * 128; idx += NTHR) {
      int row = idx >> 7, c = idx & 127;
      int span = c >> 5, cc = c & 31;
      ldsW[idx] = (unsigned short)f2bf(W[row * 1024 + span * 256 + j0 + cc]);
    }
    __syncthreads();
    #pragma unroll
    for (int n = 0; n < 2; ++n)
      #pragma unroll
      for (int kk = 0; kk < 8; ++kk) {
        frag_t f;
        #pragma unroll
        for (int j = 0; j < 8; ++j)
          f[j] = (short)ldsW[(kk * 32 + hi2 * 8 + j) * 128 + (wv * 32 + n * 16 + lo4)];
        fB[ws][n][kk] = f;
      }
    __syncthreads();
    const float* Wx = ws ? Wx2 : Wx1;
    for (int idx = tid; idx < INDIM * 128; idx += NTHR) {
      int row = idx >> 7, c = idx & 127;
      int span = c >> 5, cc = c & 31;
      ldsW[idx] = (unsigned short)f2bf(Wx[row * 1024 + span * 256 + j0 + cc]);
    }
    __syncthreads();
    #pragma unroll
    for (int n = 0; n < 2; ++n) {
      frag_t f;
      #pragma unroll
      for (int j = 0; j < 8; ++j) {
        int k = hi2 * 8 + j;
        short v = 0;
        if (k < INDIM) v = (short)ldsW[k * 128 + (wv * 32 + n * 16 + lo4)];
        f[j] = v;
      }
      fB[ws][n][8] = f;
    }
    __syncthreads();
  }

  if (tid < 128) {
    int span = tid >> 5, cc = tid & 31;
    biasLds[0][tid] = b1[span * 256 + j0 + cc];
    biasLds[1][tid] = b2[span * 256 + j0 + cc];
  }
  if (tid < HC) linWs[tid] = linW[j0 + tid];
  for (int idx = tid; idx < NEMB_ * HC; idx += NTHR) {
    int id = idx >> 5, j = idx & 31;
    float s = be[j0 + j];
    #pragma unroll
    for (int k = 0; k < EE; ++k) s += embt[id * EE + k] * We[k * HH + j0 + j];
    alphaTab[id][j] = sigf(s);
  }
  __syncthreads();

  // ---------------- main scan ----------------
  const int bcell = tid & 15, jp = tid >> 4;   // producer: batch=bcell, hidden 2jp,2jp+1
  const int srow  = tid >> 4, scol8 = tid & 15; // consumer: row srow, u64 slots scol8*8..+8
  const float lw0 = linWs[2 * jp], lw1 = linWs[2 * jp + 1];
  const float lb = linb[0];
  float c0 = 0.f, c1 = 0.f;
  bool slowmode = false;   // per-thread permanent fallback switch

  // initial x fragment + e indices (t = 0)
  frag_t ax;
  #pragma unroll
  for (int j = 0; j < 8; ++j) ax[j] = 0;
  if (hi2 < 2) {
    const float4* p = (const float4*)(x + ((size_t)(g * MB + lo4) * SS + 0) * INDIM + hi2 * 8);
    float4 v0 = p[0], v1 = p[1];
    ax[0] = f2bf(v0.x); ax[1] = f2bf(v0.y); ax[2] = f2bf(v0.z); ax[3] = f2bf(v0.w);
    ax[4] = f2bf(v1.x); ax[5] = f2bf(v1.y); ax[6] = f2bf(v1.z); ax[7] = f2bf(v1.w);
  }
  int e4v[4];
  #pragma unroll
  for (int r = 0; r < 4; ++r) e4v[r] = e[(size_t)(g * MB + hi2 * 4 + r) * SS + 0];

  const size_t prodIdx = (size_t)bcell * 128 + (size_t)ch * 16 + jp;
  const size_t consIdx = (size_t)srow * 128 + (size_t)scol8 * 8;

  for (int t = 0; t < SS; ++t) {
    const int par = t & 1;

    // (P0) x-MFMAs first: independent of h, runs while producers' stores land
    f32x4 acc[2][2];
    #pragma unroll
    for (int a = 0; a < 2; ++a)
      #pragma unroll
      for (int n = 0; n < 2; ++n) { f32x4 z = {0.f, 0.f, 0.f, 0.f}; acc[a][n] = z; }
    acc[0][0] = __builtin_amdgcn_mfma_f32_16x16x32_bf16(ax, fB[0][0][8], acc[0][0], 0, 0, 0);
    acc[0][1] = __builtin_amdgcn_mfma_f32_16x16x32_bf16(ax, fB[0][1][8], acc[0][1], 0, 0, 0);
    acc[1][0] = __builtin_amdgcn_mfma_f32_16x16x32_bf16(ax, fB[1][0][8], acc[1][0], 0, 0, 0);
    acc[1][1] = __builtin_amdgcn_mfma_f32_16x16x32_bf16(ax, fB[1][1][8], acc[1][1], 0, 0, 0);

    // (P1) poll tagged h data: tag==t means payload (same 8B) is step-t h.
    //      Fast: sc0 loads on hxF (local-L2). Bounded; fallback to hxS.
    ull v0, v1, v2, v3, v4, v5, v6, v7;
    {
      const ull tg = (ull)(unsigned)t;
      bool got = false;
      if (!slowmode) {
        const ull* srcF = hxF + (size_t)(par * NGRP + g) * 2048 + consIdx;
        int iter = 0;
        union QU { i32x4 q; ull d[2]; } u0, u1, u2, u3;
        while (iter < FAST_SOFT) {
          i32x4 q0, q1, q2, q3;
          asm volatile(
              "global_load_dwordx4 %0, %4, off sc0\n\t"
              "global_load_dwordx4 %1, %4, off offset:16 sc0\n\t"
              "global_load_dwordx4 %2, %4, off offset:32 sc0\n\t"
              "global_load_dwordx4 %3, %4, off offset:48 sc0\n\t"
              "s_waitcnt vmcnt(0)"
              : "=&v"(q0), "=&v"(q1), "=&v"(q2), "=&v"(q3)
              : "v"(srcF)
              : "memory");
          __builtin_amdgcn_sched_barrier(0);
          u0.q = q0; u1.q = q1; u2.q = q2; u3.q = q3;
          bool ok = ((u0.d[0] >> 32) == tg) & ((u0.d[1] >> 32) == tg) &
                    ((u1.d[0] >> 32) == tg) & ((u1.d[1] >> 32) == tg) &
                    ((u2.d[0] >> 32) == tg) & ((u2.d[1] >> 32) == tg) &
                    ((u3.d[0] >> 32) == tg) & ((u3.d[1] >> 32) == tg);
          ++iter;
          if (ok) { got = true; break; }
        }
        if (got) {
          v0 = u0.d[0]; v1 = u0.d[1]; v2 = u1.d[0]; v3 = u1.d[1];
          v4 = u2.d[0]; v5 = u2.d[1]; v6 = u3.d[0]; v7 = u3.d[1];
        } else {
          slowmode = true;   // permanent: this thread polls hxS from now on
        }
      }
      if (!got) {
        const ull* src = hxS + (size_t)(par * NGRP + g) * 2048 + consIdx;
        for (;;) {
          v0 = AL(&src[0]); v1 = AL(&src[1]); v2 = AL(&src[2]); v3 = AL(&src[3]);
          v4 = AL(&src[4]); v5 = AL(&src[5]); v6 = AL(&src[6]); v7 = AL(&src[7]);
          bool ok = ((v0 >> 32) == tg) & ((v1 >> 32) == tg) &
                    ((v2 >> 32) == tg) & ((v3 >> 32) == tg) &
                    ((v4 >> 32) == tg) & ((v5 >> 32) == tg) &
                    ((v6 >> 32) == tg) & ((v7 >> 32) == tg);
          if (ok) break;
        }
      }
    }

    // (P2) strip tags -> LDS h tile (32B/thread, two b128 writes)
    {
      uint4 w0 = { (unsigned)v0, (unsigned)v1, (unsigned)v2, (unsigned)v3 };
      uint4 w1 = { (unsigned)v4, (unsigned)v5, (unsigned)v6, (unsigned)v7 };
      *(uint4*)&hstageU[srow][scol8 * 8]     = w0;
      *(uint4*)&hstageU[srow][scol8 * 8 + 4] = w1;
    }
    LBAR();

    // (P3) issue next-step x/e prefetch; stays in flight across the LDS-only
    //      barriers, consumed at (P7)
    float4 xn0, xn1; int e4n[4];
    if (t + 1 < SS) {
      if (hi2 < 2) {
        const float4* p =
            (const float4*)(x + ((size_t)(g * MB + lo4) * SS + (t + 1)) * INDIM + hi2 * 8);
        xn0 = p[0]; xn1 = p[1];
      }
      #pragma unroll
      for (int r = 0; r < 4; ++r)
        e4n[r] = e[(size_t)(g * MB + hi2 * 4 + r) * SS + (t + 1)];
    }

    // (P4) h-MFMAs from LDS fragments
    #pragma unroll
    for (int kk = 0; kk < 8; ++kk) {
      frag_t ah = *(const frag_t*)&hstageU[lo4][kk * 16 + hi2 * 4];
      acc[0][0] = __builtin_amdgcn_mfma_f32_16x16x32_bf16(ah, fB[0][0][kk], acc[0][0], 0, 0, 0);
      acc[0][1] = __builtin_amdgcn_mfma_f32_16x16x32_bf16(ah, fB[0][1][kk], acc[0][1], 0, 0, 0);
      acc[1][0] = __builtin_amdgcn_mfma_f32_16x16x32_bf16(ah, fB[1][0][kk], acc[1][0], 0, 0, 0);
      acc[1][1] = __builtin_amdgcn_mfma_f32_16x16x32_bf16(ah, fB[1][1][kk], acc[1][1], 0, 0, 0);
    }

    // (P5) alpha-interpolate + bias -> gatesLds (C layout: col=lane&15, row=hi2*4+r)
    #pragma unroll
    for (int n = 0; n < 2; ++n) {
      const float bb1 = biasLds[0][wv * 32 + n * 16 + lo4];
      const float bb2 = biasLds[1][wv * 32 + n * 16 + lo4];
      #pragma unroll
      for (int r = 0; r < 4; ++r) {
        const float a = alphaTab[e4v[r]][n * 16 + lo4];
        const float p1 = acc[0][n][r] + bb1;
        const float p2 = acc[1][n][r] + bb2;
        gatesLds[wv][hi2 * 4 + r][n * 16 + lo4] = a * p1 + (1.f - a) * p2;
      }
    }
    LBAR();

    // (P6) cell update; DUAL publish: plain store to hxF (local L2, fast) +
    //      memory-side swap to hxS (guaranteed). Identical payloads -> output
    //      is path-independent.
    {
      const float gi0 = gatesLds[0][bcell][2 * jp];
      const float gf0 = gatesLds[1][bcell][2 * jp];
      const float gg0 = gatesLds[2][bcell][2 * jp];
      const float go0 = gatesLds[3][bcell][2 * jp];
      const float gi1 = gatesLds[0][bcell][2 * jp + 1];
      const float gf1 = gatesLds[1][bcell][2 * jp + 1];
      const float gg1 = gatesLds[2][bcell][2 * jp + 1];
      const float go1 = gatesLds[3][bcell][2 * jp + 1];
      c0 = sigf(gf0) * c0 + sigf(gi0) * tanh_fast(gg0);
      c1 = sigf(gf1) * c1 + sigf(gi1) * tanh_fast(gg1);
      const float h0 = sigf(go0) * tanh_fast(c0);
      const float h1 = sigf(go1) * tanh_fast(c1);
      if (t + 1 < SS) {
        const uint32_t pk = (uint32_t)(uint16_t)f2bf(h0) | ((uint32_t)(uint16_t)f2bf(h1) << 16);
        const ull pv = ((ull)(unsigned)(t + 1) << 32) | (ull)pk;
        const size_t off = (size_t)(((par ^ 1) * NGRP) + g) * 2048 + prodIdx;
        ull* dstF = &hxF[off];
        ull* dstS = &hxS[off];
        asm volatile("global_store_dwordx2 %0, %1, off" :: "v"(dstF), "v"(pv) : "memory");
        asm volatile("global_atomic_swap_x2 %0, %1, off sc1" :: "v"(dstS), "v"(pv) : "memory");
      }
      redbuf[jp][bcell] = h0 * lw0 + h1 * lw1;
    }
    LBAR();

    // (P7) convert prefetched x/e (overlaps peers' detect window), out-reduce
    if (t + 1 < SS) {
      frag_t f;
      #pragma unroll
      for (int j = 0; j < 8; ++j) f[j] = 0;
      if (hi2 < 2) {
        f[0] = f2bf(xn0.x); f[1] = f2bf(xn0.y); f[2] = f2bf(xn0.z); f[3] = f2bf(xn0.w);
        f[4] = f2bf(xn1.x); f[5] = f2bf(xn1.y); f[6] = f2bf(xn1.z); f[7] = f2bf(xn1.w);
      }
      ax = f;
      #pragma unroll
      for (int r = 0; r < 4; ++r) e4v[r] = e4n[r];
    }
    if (tid >= 16 && tid < 32) {
      const int b = tid - 16;
      float s = 0.f;
      #pragma unroll
      for (int q = 0; q < MB; ++q) s += redbuf[q][b];
      if (use_partial) {
        partial[((size_t)(g * NCHK + ch) * MB + b) * SS + t] = s;
      } else {
        atomicAdd(&out[(size_t)(g * MB + b) * SS + t], s + ((ch == 0) ? lb : 0.f));
      }
    }
  }
}

__global__ __launch_bounds__(256)
void sum_out_kernel(const float* __restrict__ partial, const float* __restrict__ linb,
                    float* __restrict__ out) {
  const int i = blockIdx.x * 256 + threadIdx.x;      // over BB*SS
  if (i >= BB * SS) return;
  const int b = i >> 10, t = i & 1023;
  const int g = b >> 4, bb = b & 15;
  const float* p = partial + ((size_t)g * NCHK * MB + bb) * SS + t;
  float s = linb[0];
  #pragma unroll
  for (int c = 0; c < NCHK; ++c) s += p[(size_t)c * MB * SS];
  out[i] = s;
}

extern "C" void kernel_launch(void* const* d_in, const int* in_sizes, int n_in,
                              void* d_out, int out_size, void* d_ws, size_t ws_size,
                              hipStream_t stream) {
  const int*   e    = (const int*)d_in[0];
  const float* x    = (const float*)d_in[1];
  const float* embt = (const float*)d_in[2];
  const float* Wx1  = (const float*)d_in[3];
  const float* Wx2  = (const float*)d_in[4];
  const float* Wh1  = (const float*)d_in[5];
  const float* Wh2  = (const float*)d_in[6];
  const float* b1   = (const float*)d_in[7];
  const float* b2   = (const float*)d_in[8];
  const float* We   = (const float*)d_in[9];
  const float* be   = (const float*)d_in[10];
  const float* linW = (const float*)d_in[11];
  const float* linb = (const float*)d_in[12];
  float* out = (float*)d_out;

  const size_t hx_bytes = (size_t)2 * NGRP * MB * 128 * sizeof(ull);  // 256KB each
  ull* hxS = (ull*)d_ws;
  ull* hxF = (ull*)((char*)d_ws + hx_bytes);
  const size_t part_bytes = (size_t)NBLK * MB * SS * sizeof(float);   // 4MB
  float* partial = (float*)((char*)d_ws + 2 * hx_bytes);
  const int use_partial = (ws_size >= 2 * hx_bytes + part_bytes) ? 1 : 0;

  hipMemsetAsync(d_out, 0, (size_t)BB * SS * sizeof(float), stream);
  hipMemsetAsync(d_ws, 0, 2 * hx_bytes, stream);  // tags=0 == step-0 target; h0=0

  void* args[] = { (void*)&e, (void*)&x, (void*)&embt, (void*)&Wx1, (void*)&Wx2,
                   (void*)&Wh1, (void*)&Wh2, (void*)&b1, (void*)&b2, (void*)&We,
                   (void*)&be, (void*)&linW, (void*)&linb, (void*)&out,
                   (void*)&hxS, (void*)&hxF, (void*)&partial, (void*)&use_partial };
  hipError_t err = hipLaunchCooperativeKernel(reinterpret_cast<void*>(ilstm_kernel),
                                              dim3(NBLK), dim3(NTHR),
                                              args, 0, stream);
  if (err != hipSuccess) {
    // fallback: plain launch; 64 blocks <= 256 CUs -> co-resident
    ilstm_kernel<<<dim3(NBLK), dim3(NTHR), 0, stream>>>(
        e, x, embt, Wx1, Wx2, Wh1, Wh2, b1, b2, We, be, linW, linb, out, hxS, hxF,
        partial, use_partial);
  }
  if (use_partial) {
    sum_out_kernel<<<dim3((BB * SS + 255) / 256), dim3(256), 0, stream>>>(
        partial, linb, out);
  }
}

// Round 14
// 2441.321 us; speedup vs baseline: 1.9421x; 1.9421x over previous
//
#include <hip/hip_runtime.h>
#include <hip/hip_bf16.h>
#include <cstdint>
#include <cstddef>

// Problem dims
#define BB    128
#define SS    1024
#define INDIM 16
#define HH    256
#define EE    32
#define NEMB_ 64

// Decomposition
#define NGRP 8    // batch groups
#define MB   16   // batches per group
#define NCHK 8    // hidden chunks (8 blocks per group)
#define HC   32   // hidden units per chunk (block computes 4*HC=128 gate cols)
#define NTHR 256  // 4 waves; wave w owns gate-type w
#define NBLK 64   // 8 groups x 8 chunks

using frag_t = __attribute__((ext_vector_type(8))) short;  // 8 bf16 (4 VGPRs)
using f32x4  = __attribute__((ext_vector_type(4))) float;
typedef unsigned long long ull;

#define AL(p)    __hip_atomic_load((p),  __ATOMIC_RELAXED, __HIP_MEMORY_SCOPE_AGENT)

// LDS-only barrier: does NOT drain vmcnt (unlike __syncthreads), so global
// loads/stores stay in flight across it. lgkmcnt(0) orders the ds_writes.
#define LBAR() do { asm volatile("s_waitcnt lgkmcnt(0)" ::: "memory"); \
  __builtin_amdgcn_s_barrier(); __builtin_amdgcn_sched_barrier(0); } while (0)

__device__ __forceinline__ short f2bf(float f) {
  union { float f; uint32_t u; } v; v.f = f;
  uint32_t r = (v.u + 0x7fffu + ((v.u >> 16) & 1u)) >> 16;  // RNE
  return (short)(uint16_t)r;
}
__device__ __forceinline__ float sigf(float x) { return 1.0f / (1.0f + __expf(-x)); }
__device__ __forceinline__ float tanh_fast(float x) { return 1.0f - 2.0f / (__expf(2.0f * x) + 1.0f); }

// Exchange: hx[par][g][row=batch][slot=hidden_pair] : u64 = (tag<<32)|(2xbf16).
// Published via memory-side atomic swap sc1; polled via sc1 atomic loads.
// (R12-proven transport: both op classes execute at the coherence point.)

__global__ __launch_bounds__(NTHR, 1)
void ilstm_kernel(const int* __restrict__ e, const float* __restrict__ x,
                  const float* __restrict__ embt, const float* __restrict__ Wx1,
                  const float* __restrict__ Wx2, const float* __restrict__ Wh1,
                  const float* __restrict__ Wh2, const float* __restrict__ b1,
                  const float* __restrict__ b2, const float* __restrict__ We,
                  const float* __restrict__ be, const float* __restrict__ linW,
                  const float* __restrict__ linb, float* __restrict__ out,
                  ull* __restrict__ hx, float* __restrict__ partial,
                  int use_partial)
{
  const int tid  = threadIdx.x;
  const int bid  = blockIdx.x;
  const int g    = bid & 7;        // batch group
  const int ch   = bid >> 3;       // hidden chunk
  const int j0   = ch * HC;
  const int lane = tid & 63;
  const int wv   = tid >> 6;       // wave id == gate type (i,f,g,o)
  const int lo4  = lane & 15;
  const int hi2  = lane >> 4;

  __shared__ unsigned short ldsW[HH * 128];        // 64KB weight staging (init only)
  __shared__ unsigned hstageU[2][MB][132];         // 2x 8.4KB h tile, PARITY dbuf
  __shared__ float alphaTab[NEMB_][HC];            // 8KB sigmoid(emb@We+be)
  __shared__ float gatesLds[2][4][MB][HC + 1];     // PARITY dbuf gate exchange
  __shared__ float redbuf[2][MB][MB + 1];          // PARITY dbuf out partials
  __shared__ float biasLds[2][128];
  __shared__ float linWs[HC];

  // ---------------- init: weights -> B-fragments in VGPRs ----------------
  frag_t fB[2][2][9];  // [W1/W2][ntile][kstep]; kstep 8 = x-projection (K rows 16..31 zero)
  #pragma unroll
  for (int ws = 0; ws < 2; ++ws) {
    const float* W = ws ? Wh2 : Wh1;
    for (int idx = tid; idx < HH * 128; idx += NTHR) {
      int row = idx >> 7, c = idx & 127;
      int span = c >> 5, cc = c & 31;
      ldsW[idx] = (unsigned short)f2bf(W[row * 1024 + span * 256 + j0 + cc]);
    }
    __syncthreads();
    #pragma unroll
    for (int n = 0; n < 2; ++n)
      #pragma unroll
      for (int kk = 0; kk < 8; ++kk) {
        frag_t f;
        #pragma unroll
        for (int j = 0; j < 8; ++j)
          f[j] = (short)ldsW[(kk * 32 + hi2 * 8 + j) * 128 + (wv * 32 + n * 16 + lo4)];
        fB[ws][n][kk] = f;
      }
    __syncthreads();
    const float* Wx = ws ? Wx2 : Wx1;
    for (int idx = tid; idx < INDIM * 128; idx += NTHR) {
      int row = idx >> 7, c = idx & 127;
      int span = c >> 5, cc = c & 31;
      ldsW[idx] = (unsigned short)f2bf(Wx[row * 1024 + span * 256 + j0 + cc]);
    }
    __syncthreads();
    #pragma unroll
    for (int n = 0; n < 2; ++n) {
      frag_t f;
      #pragma unroll
      for (int j = 0; j < 8; ++j) {
        int k = hi2 * 8 + j;
        short v = 0;
        if (k < INDIM) v = (short)ldsW[k * 128 + (wv * 32 + n * 16 + lo4)];
        f[j] = v;
      }
      fB[ws][n][8] = f;
    }
    __syncthreads();
  }

  if (tid < 128) {
    int span = tid >> 5, cc = tid & 31;
    biasLds[0][tid] = b1[span * 256 + j0 + cc];
    biasLds[1][tid] = b2[span * 256 + j0 + cc];
  }
  if (tid < HC) linWs[tid] = linW[j0 + tid];
  for (int idx = tid; idx < NEMB_ * HC; idx += NTHR) {
    int id = idx >> 5, j = idx & 31;
    float s = be[j0 + j];
    #pragma unroll
    for (int k = 0; k < EE; ++k) s += embt[id * EE + k] * We[k * HH + j0 + j];
    alphaTab[id][j] = sigf(s);
  }
  __syncthreads();

  // ---------------- main scan ----------------
  const int bcell = tid & 15, jp = tid >> 4;   // producer: batch=bcell, hidden 2jp,2jp+1
  const int srow  = tid >> 4, scol8 = tid & 15; // consumer: row srow, u64 slots scol8*8..+8
  const float lw0 = linWs[2 * jp], lw1 = linWs[2 * jp + 1];
  const float lb = linb[0];
  float c0 = 0.f, c1 = 0.f;

  // initial x fragment + e indices (t = 0)
  frag_t ax;
  #pragma unroll
  for (int j = 0; j < 8; ++j) ax[j] = 0;
  if (hi2 < 2) {
    const float4* p = (const float4*)(x + ((size_t)(g * MB + lo4) * SS + 0) * INDIM + hi2 * 8);
    float4 v0 = p[0], v1 = p[1];
    ax[0] = f2bf(v0.x); ax[1] = f2bf(v0.y); ax[2] = f2bf(v0.z); ax[3] = f2bf(v0.w);
    ax[4] = f2bf(v1.x); ax[5] = f2bf(v1.y); ax[6] = f2bf(v1.z); ax[7] = f2bf(v1.w);
  }
  int e4v[4];
  #pragma unroll
  for (int r = 0; r < 4; ++r) e4v[r] = e[(size_t)(g * MB + hi2 * 4 + r) * SS + 0];

  const size_t prodIdx = (size_t)bcell * 128 + (size_t)ch * 16 + jp;
  const size_t consIdx = (size_t)srow * 128 + (size_t)scol8 * 8;

  for (int t = 0; t < SS; ++t) {
    const int par = t & 1;

    // (P0) x-MFMAs first: independent of h, runs while producers' swaps land
    f32x4 acc[2][2];
    #pragma unroll
    for (int a = 0; a < 2; ++a)
      #pragma unroll
      for (int n = 0; n < 2; ++n) { f32x4 z = {0.f, 0.f, 0.f, 0.f}; acc[a][n] = z; }
    acc[0][0] = __builtin_amdgcn_mfma_f32_16x16x32_bf16(ax, fB[0][0][8], acc[0][0], 0, 0, 0);
    acc[0][1] = __builtin_amdgcn_mfma_f32_16x16x32_bf16(ax, fB[0][1][8], acc[0][1], 0, 0, 0);
    acc[1][0] = __builtin_amdgcn_mfma_f32_16x16x32_bf16(ax, fB[1][0][8], acc[1][0], 0, 0, 0);
    acc[1][1] = __builtin_amdgcn_mfma_f32_16x16x32_bf16(ax, fB[1][1][8], acc[1][1], 0, 0, 0);

    // (P1) poll tagged h data: tag==t means payload (same 8B) is step-t h
    ull v0, v1, v2, v3, v4, v5, v6, v7;
    {
      const ull* src = hx + (size_t)(par * NGRP + g) * 2048 + consIdx;
      const ull tg = (ull)(unsigned)t;
      for (;;) {
        v0 = AL(&src[0]); v1 = AL(&src[1]); v2 = AL(&src[2]); v3 = AL(&src[3]);
        v4 = AL(&src[4]); v5 = AL(&src[5]); v6 = AL(&src[6]); v7 = AL(&src[7]);
        bool ok = ((v0 >> 32) == tg) & ((v1 >> 32) == tg) &
                  ((v2 >> 32) == tg) & ((v3 >> 32) == tg) &
                  ((v4 >> 32) == tg) & ((v5 >> 32) == tg) &
                  ((v6 >> 32) == tg) & ((v7 >> 32) == tg);
        if (ok) break;
      }
    }

    // (P2) strip tags -> LDS h tile (parity buffer; 32B/thread, two b128 writes)
    {
      uint4 w0 = { (unsigned)v0, (unsigned)v1, (unsigned)v2, (unsigned)v3 };
      uint4 w1 = { (unsigned)v4, (unsigned)v5, (unsigned)v6, (unsigned)v7 };
      *(uint4*)&hstageU[par][srow][scol8 * 8]     = w0;
      *(uint4*)&hstageU[par][srow][scol8 * 8 + 4] = w1;
    }

    // (P2b) issue next-step x/e prefetch BEFORE the barrier (in flight across
    //       it; consumed at P7)
    float4 xn0, xn1; int e4n[4];
    if (t + 1 < SS) {
      if (hi2 < 2) {
        const float4* p =
            (const float4*)(x + ((size_t)(g * MB + lo4) * SS + (t + 1)) * INDIM + hi2 * 8);
        xn0 = p[0]; xn1 = p[1];
      }
      #pragma unroll
      for (int r = 0; r < 4; ++r)
        e4n[r] = e[(size_t)(g * MB + hi2 * 4 + r) * SS + (t + 1)];
    }
    LBAR();   // barrier 1 of 2: seals hstageU[par] + (transitively) redbuf[par^1]

    // (P3) out-reduce for step t-1 in the MFMA shadow (redbuf[par^1] sealed)
    if (t > 0 && tid >= 16 && tid < 32) {
      const int b = tid - 16;
      float s = 0.f;
      #pragma unroll
      for (int q = 0; q < MB; ++q) s += redbuf[par ^ 1][q][b];
      if (use_partial) {
        partial[((size_t)(g * NCHK + ch) * MB + b) * SS + (t - 1)] = s;
      } else {
        atomicAdd(&out[(size_t)(g * MB + b) * SS + (t - 1)], s + ((ch == 0) ? lb : 0.f));
      }
    }

    // (P4) h-MFMAs from LDS fragments
    #pragma unroll
    for (int kk = 0; kk < 8; ++kk) {
      frag_t ah = *(const frag_t*)&hstageU[par][lo4][kk * 16 + hi2 * 4];
      acc[0][0] = __builtin_amdgcn_mfma_f32_16x16x32_bf16(ah, fB[0][0][kk], acc[0][0], 0, 0, 0);
      acc[0][1] = __builtin_amdgcn_mfma_f32_16x16x32_bf16(ah, fB[0][1][kk], acc[0][1], 0, 0, 0);
      acc[1][0] = __builtin_amdgcn_mfma_f32_16x16x32_bf16(ah, fB[1][0][kk], acc[1][0], 0, 0, 0);
      acc[1][1] = __builtin_amdgcn_mfma_f32_16x16x32_bf16(ah, fB[1][1][kk], acc[1][1], 0, 0, 0);
    }

    // (P5) alpha-interpolate + bias -> gatesLds[par]
    #pragma unroll
    for (int n = 0; n < 2; ++n) {
      const float bb1 = biasLds[0][wv * 32 + n * 16 + lo4];
      const float bb2 = biasLds[1][wv * 32 + n * 16 + lo4];
      #pragma unroll
      for (int r = 0; r < 4; ++r) {
        const float a = alphaTab[e4v[r]][n * 16 + lo4];
        const float p1 = acc[0][n][r] + bb1;
        const float p2 = acc[1][n][r] + bb2;
        gatesLds[par][wv][hi2 * 4 + r][n * 16 + lo4] = a * p1 + (1.f - a) * p2;
      }
    }
    LBAR();   // barrier 2 of 2: seals gatesLds[par]

    // (P6) cell update; publish swap ISSUES FIRST, bookkeeping after
    {
      const float gi0 = gatesLds[par][0][bcell][2 * jp];
      const float gf0 = gatesLds[par][1][bcell][2 * jp];
      const float gg0 = gatesLds[par][2][bcell][2 * jp];
      const float go0 = gatesLds[par][3][bcell][2 * jp];
      const float gi1 = gatesLds[par][0][bcell][2 * jp + 1];
      const float gf1 = gatesLds[par][1][bcell][2 * jp + 1];
      const float gg1 = gatesLds[par][2][bcell][2 * jp + 1];
      const float go1 = gatesLds[par][3][bcell][2 * jp + 1];
      c0 = sigf(gf0) * c0 + sigf(gi0) * tanh_fast(gg0);
      c1 = sigf(gf1) * c1 + sigf(gi1) * tanh_fast(gg1);
      const float h0 = sigf(go0) * tanh_fast(c0);
      const float h1 = sigf(go1) * tanh_fast(c1);
      if (t + 1 < SS) {
        const uint32_t pk = (uint32_t)(uint16_t)f2bf(h0) | ((uint32_t)(uint16_t)f2bf(h1) << 16);
        const ull pv = ((ull)(unsigned)(t + 1) << 32) | (ull)pk;
        ull* dst = &hx[(size_t)(((par ^ 1) * NGRP) + g) * 2048 + prodIdx];
        asm volatile("global_atomic_swap_x2 %0, %1, off sc1"
                     :: "v"(dst), "v"(pv) : "memory");
      }
      redbuf[par][jp][bcell] = h0 * lw0 + h1 * lw1;   // read next step in shadow
    }

    // (P7) convert prefetched x/e (overlaps peers' detect window)
    if (t + 1 < SS) {
      frag_t f;
      #pragma unroll
      for (int j = 0; j < 8; ++j) f[j] = 0;
      if (hi2 < 2) {
        f[0] = f2bf(xn0.x); f[1] = f2bf(xn0.y); f[2] = f2bf(xn0.z); f[3] = f2bf(xn0.w);
        f[4] = f2bf(xn1.x); f[5] = f2bf(xn1.y); f[6] = f2bf(xn1.z); f[7] = f2bf(xn1.w);
      }
      ax = f;
      #pragma unroll
      for (int r = 0; r < 4; ++r) e4v[r] = e4n[r];
    }
  }

  // epilogue: reduce the last step's redbuf
  __syncthreads();
  if (tid >= 16 && tid < 32) {
    const int parL = (SS - 1) & 1;
    const int b = tid - 16;
    float s = 0.f;
    #pragma unroll
    for (int q = 0; q < MB; ++q) s += redbuf[parL][q][b];
    if (use_partial) {
      partial[((size_t)(g * NCHK + ch) * MB + b) * SS + (SS - 1)] = s;
    } else {
      atomicAdd(&out[(size_t)(g * MB + b) * SS + (SS - 1)], s + ((ch == 0) ? lb : 0.f));
    }
  }
}

__global__ __launch_bounds__(256)
void sum_out_kernel(const float* __restrict__ partial, const float* __restrict__ linb,
                    float* __restrict__ out) {
  const int i = blockIdx.x * 256 + threadIdx.x;      // over BB*SS
  if (i >= BB * SS) return;
  const int b = i >> 10, t = i & 1023;
  const int g = b >> 4, bb = b & 15;
  const float* p = partial + ((size_t)g * NCHK * MB + bb) * SS + t;
  float s = linb[0];
  #pragma unroll
  for (int c = 0; c < NCHK; ++c) s += p[(size_t)c * MB * SS];
  out[i] = s;
}

extern "C" void kernel_launch(void* const* d_in, const int* in_sizes, int n_in,
                              void* d_out, int out_size, void* d_ws, size_t ws_size,
                              hipStream_t stream) {
  const int*   e    = (const int*)d_in[0];
  const float* x    = (const float*)d_in[1];
  const float* embt = (const float*)d_in[2];
  const float* Wx1  = (const float*)d_in[3];
  const float* Wx2  = (const float*)d_in[4];
  const float* Wh1  = (const float*)d_in[5];
  const float* Wh2  = (const float*)d_in[6];
  const float* b1   = (const float*)d_in[7];
  const float* b2   = (const float*)d_in[8];
  const float* We   = (const float*)d_in[9];
  const float* be   = (const float*)d_in[10];
  const float* linW = (const float*)d_in[11];
  const float* linb = (const float*)d_in[12];
  float* out = (float*)d_out;

  ull* hx = (ull*)d_ws;
  const size_t hx_bytes = (size_t)2 * NGRP * MB * 128 * sizeof(ull);  // 256KB
  const size_t part_bytes = (size_t)NBLK * MB * SS * sizeof(float);   // 4MB
  float* partial = (float*)((char*)d_ws + hx_bytes);
  const int use_partial = (ws_size >= hx_bytes + part_bytes) ? 1 : 0;

  hipMemsetAsync(d_out, 0, (size_t)BB * SS * sizeof(float), stream);
  hipMemsetAsync(d_ws, 0, hx_bytes, stream);   // tags=0 == step-0 target; data=h0=0

  void* args[] = { (void*)&e, (void*)&x, (void*)&embt, (void*)&Wx1, (void*)&Wx2,
                   (void*)&Wh1, (void*)&Wh2, (void*)&b1, (void*)&b2, (void*)&We,
                   (void*)&be, (void*)&linW, (void*)&linb, (void*)&out, (void*)&hx,
                   (void*)&partial, (void*)&use_partial };
  hipError_t err = hipLaunchCooperativeKernel(reinterpret_cast<void*>(ilstm_kernel),
                                              dim3(NBLK), dim3(NTHR),
                                              args, 0, stream);
  if (err != hipSuccess) {
    // fallback: plain launch; 64 blocks <= 256 CUs -> co-resident
    ilstm_kernel<<<dim3(NBLK), dim3(NTHR), 0, stream>>>(
        e, x, embt, Wx1, Wx2, Wh1, Wh2, b1, b2, We, be, linW, linb, out, hx,
        partial, use_partial);
  }
  if (use_partial) {
    sum_out_kernel<<<dim3((BB * SS + 255) / 256), dim3(256), 0, stream>>>(
        partial, linb, out);
  }
}